// Round 11
// baseline (363.010 us; speedup 1.0000x reference)
//
#include <hip/hip_runtime.h>
#include <hip/hip_fp16.h>

#define N_ROWS 32768
#define KCODES 8192
#define CDIM   256
#define NSUB   (KCODES / 16)     // 512 subtiles of 16 codes
// dot-scale margin: covers bf16-dot err + fp16-RTZ storage (~3e-5) + e2 spread (<=1.9e-6).
// Certified need ~1.05e-4; rounds 2-10 passed with this exact value + raw-dot-max semantics.
#define MARGIN_DOT 2.2e-4f
#define CAP_ROW 15               // per-row candidate cap (mean 1.7); overflow -> 0xFFFF marker
#define CAP_BIN 1024             // per-subtile LDS list cap (mean ~107); overflow -> exact fallback

typedef __attribute__((ext_vector_type(8))) short bf16x8;
typedef __attribute__((ext_vector_type(4))) float f32x4;

// async global->LDS, 16B per lane; LDS dest is wave-uniform base + lane*16 (linear),
// so XOR swizzles are applied to the per-lane GLOBAL source address instead (rule #21).
#define GLOAD_LDS16(g, l)                                                              \
    __builtin_amdgcn_global_load_lds((const __attribute__((address_space(1))) void*)(g), \
                                     (__attribute__((address_space(3))) void*)(l), 16, 0, 0)

__device__ __forceinline__ ushort f2bf_rne(float f) {
    unsigned u = __float_as_uint(f);
    u += 0x7fffu + ((u >> 16) & 1u);
    return (ushort)(u >> 16);
}

// ---------- phase 0: fp32->bf16 convert + row sum-of-squares + bestG init ----------
__global__ void prep_kernel(const float* __restrict__ x, const float* __restrict__ wgt,
                            ushort* __restrict__ xb, ushort* __restrict__ wb,
                            float* __restrict__ t1, float* __restrict__ e2,
                            unsigned long long* __restrict__ bestG) {
    const int gtid = blockIdx.x * blockDim.x + threadIdx.x;
    if (gtid < N_ROWS) bestG[gtid] = ~0ull;      // init per-row best key

    int wave = gtid >> 6;
    int lane = threadIdx.x & 63;
    const float* src; ushort* bdst; float* sqdst; int row;
    if (wave < N_ROWS) { src = x; bdst = xb; sqdst = t1; row = wave; }
    else               { src = wgt; bdst = wb; sqdst = e2; row = wave - N_ROWS; }
    float4 v = *((const float4*)src + (size_t)row * (CDIM / 4) + lane);
    ushort4 o;
    o.x = f2bf_rne(v.x); o.y = f2bf_rne(v.y); o.z = f2bf_rne(v.z); o.w = f2bf_rne(v.w);
    *((ushort4*)bdst + (size_t)row * (CDIM / 4) + lane) = o;
    float s = v.x * v.x + v.y * v.y + v.z * v.z + v.w * v.w;
    for (int off = 32; off; off >>= 1) s += __shfl_down(s, off, 64);
    if (lane == 0) sqdst[row] = s;
}

// ---------- phase 1: 128x128 tile, 4 waves x (64x64), BK=32 dbuf, TRANSPOSED MFMA ----------
// Round-10 finding: VGPR_Count=64 EXCLUDES the 64 AGPRs of acc[4][4] -> 128 unified
// regs/wave pins residency at 16 waves/CU regardless of LDS; the 48 KB alias bought
// nothing. The 37% MfmaUtil is gang-lockstep: 8 waves per barrier gang move in phase
// (ds_reads together, MFMAs together) and only 2 independent gangs/CU cover each
// other's stalls. This version: SAME wave tile (64x64), SAME fragment/swizzle/epilogue
// algebra (verified r3-r10), but 4-wave blocks on 128x128 tiles -> 4 independent
// barrier gangs per CU (r1-vs-r2 lesson, now register-neutral). LDS 32 KB/block.
__launch_bounds__(256, 2)
__global__ void vq_mfma_kernel(const ushort* __restrict__ xb, const ushort* __restrict__ wb,
                               __half* __restrict__ minT) {
    __shared__ ushort xs[2][128 * 32];   // 2 x 8 KB  (X: 128 rows x 32 cols)
    __shared__ ushort ws_l[2][128 * 32]; // 2 x 8 KB  (W: 128 codes x 32 cols)
    // transposed maxima scratch aliased onto xs[0] (8 x 136 x 2B = 2.1 KB); safe:
    // xs[0]'s last READ is chunk 6, all waves pass chunk 7's barrier before writes.
    ushort (*mbT)[136] = (ushort (*)[136])&xs[0][0];

    const int t = threadIdx.x;
    const int w = t >> 6, lane = t & 63;
    const int ln15 = lane & 15, quad = lane >> 4;
    const int rt = blockIdx.x >> 6;     // 256 row tiles of 128 rows
    const int ct = blockIdx.x & 63;     // 64 code tiles of 128 codes
    const int rbase = (w >> 1) * 64;    // wave x-row base (0 or 64)
    const int cbase = (w & 1) * 64;     // wave code base (0 or 64)

    // staging: per wave-call 16 rows x 32 cols (1 KB); lane l -> row +(l>>2), slot l&3;
    // source chunk (l&3)^((l>>3)&3) pre-applies the LDS swizzle (row bases % 16 == 0).
    const int srow16 = lane >> 2;
    const int schunk = (lane & 3) ^ ((lane >> 3) & 3);
    const ushort* xsrc = xb + (size_t)(rt * 128 + w * 32 + srow16) * CDIM + schunk * 8;
    const ushort* wsrc = wb + (size_t)(ct * 128 + w * 32 + srow16) * CDIM + schunk * 8;

    f32x4 acc[4][4];                    // [ni: code blocks][mi: x-row blocks]
#pragma unroll
    for (int ni = 0; ni < 4; ++ni)
#pragma unroll
        for (int mi = 0; mi < 4; ++mi)
#pragma unroll
            for (int r = 0; r < 4; ++r) acc[ni][mi][r] = 0.f;

    // prologue: stage chunk 0 -> buf 0 (X: 2 calls/wave, W: 2 calls/wave)
#pragma unroll
    for (int j = 0; j < 2; ++j) {
        GLOAD_LDS16(xsrc + (size_t)j * 16 * CDIM, &xs[0][(w * 32 + j * 16) * 32]);
        GLOAD_LDS16(wsrc + (size_t)j * 16 * CDIM, &ws_l[0][(w * 32 + j * 16) * 32]);
    }
    __syncthreads();

#pragma unroll
    for (int cc = 0; cc < 8; ++cc) {                  // 8 K-chunks of 32
        const int cur = cc & 1;
        if (cc < 7) {                                  // issue next-chunk loads FIRST
#pragma unroll
            for (int j = 0; j < 2; ++j) {
                GLOAD_LDS16(xsrc + (size_t)j * 16 * CDIM + (cc + 1) * 32,
                            &xs[cur ^ 1][(w * 32 + j * 16) * 32]);
                GLOAD_LDS16(wsrc + (size_t)j * 16 * CDIM + (cc + 1) * 32,
                            &ws_l[cur ^ 1][(w * 32 + j * 16) * 32]);
            }
        }
        const int swz = (quad ^ ((ln15 >> 1) & 3)) * 8;
        bf16x8 a[4], b[4];
#pragma unroll
        for (int ni = 0; ni < 4; ++ni)
            a[ni] = *(const bf16x8*)&ws_l[cur][(cbase + ni * 16 + ln15) * 32 + swz];
#pragma unroll
        for (int mi = 0; mi < 4; ++mi)
            b[mi] = *(const bf16x8*)&xs[cur][(rbase + mi * 16 + ln15) * 32 + swz];
#pragma unroll
        for (int ni = 0; ni < 4; ++ni)
#pragma unroll
            for (int mi = 0; mi < 4; ++mi)
                acc[ni][mi] = __builtin_amdgcn_mfma_f32_16x16x32_bf16(a[ni], b[mi], acc[ni][mi], 0, 0, 0);
        __syncthreads();          // drains vmcnt -> buf^1 ready; protects buf reuse
    }

    // epilogue (same algebra as r3-r10): codes live in {regs x quads}
#pragma unroll
    for (int mi = 0; mi < 4; ++mi) {
        float mxn[4];
#pragma unroll
        for (int ni = 0; ni < 4; ++ni) {
            f32x4 v = acc[ni][mi];
            float mx = fmaxf(fmaxf(v[0], v[1]), fmaxf(v[2], v[3]));
            mx = fmaxf(mx, __shfl_xor(mx, 16, 64));
            mx = fmaxf(mx, __shfl_xor(mx, 32, 64));
            mxn[ni] = mx;
        }
        float sel = quad == 0 ? mxn[0] : quad == 1 ? mxn[1] : quad == 2 ? mxn[2] : mxn[3];
        uint pk = __builtin_bit_cast(uint, __builtin_amdgcn_cvt_pkrtz(sel, sel));  // RTZ as certified
        mbT[(cbase >> 4) + quad][rbase + mi * 16 + ln15] = (ushort)(pk & 0xffffu);
    }
    __syncthreads();
    if (t < 128) {
        // minT layout [rt(256)][ct(64)][row(128)][sub(8)]: dense 2 KB per block
        union { ushort s[8]; uint4 u; } r;
#pragma unroll
        for (int s = 0; s < 8; ++s) r.s[s] = mbT[s][t];
        *(uint4*)(minT + ((size_t)(rt * 64 + ct) * 128 + t) * 8) = r.u;
    }
}

// ---------- phase 2a: candidate scan -> packed per-row records (NO global atomics) ----------
// (r9/r10-validated LDS-staged version; only the minT indexing reflects the new
// [rt(256)][ct(64)][row(128)][sub(8)] layout -- staged values and threshold math are
// BIT-IDENTICAL to rounds 2-10)
__launch_bounds__(256, 8)
__global__ void vq_scan_kernel(const __half* __restrict__ minT, uint* __restrict__ rowcand) {
    __shared__ ushort sm[64][136];       // [ct][row*8+sub], padded stride (17 KB)
    __shared__ ushort cand[16][16];      // [row][0]=cnt/marker, [row][1..15]=subtile ids
    const int t = threadIdx.x, w = t >> 6, lane = t & 63;
    const int row0 = blockIdx.x * 16;

    // stage: thread t covers ct = t>>2, rows 4*(t&3)..+4 (64B contiguous per thread)
    {
        const int ct = t >> 2, c4 = t & 3;
        const uint4* src = (const uint4*)(minT +
            ((((size_t)(row0 >> 7) * 64 + ct) * 128 + (row0 & 127) + c4 * 4) * 8));
#pragma unroll
        for (int i = 0; i < 4; ++i)
            *(uint4*)&sm[ct][(c4 * 4 + i) * 8] = src[i];
    }
    __syncthreads();

    for (int i = 0; i < 4; ++i) {
        const int rr = w * 4 + i;
        union { uint4 u; __half2 h2[4]; } raw;
        raw.u = *(const uint4*)&sm[lane][rr * 8];    // same values as rounds 2-10
        float m[8];
#pragma unroll
        for (int q = 0; q < 4; ++q) {
            float2 f = __half22float2(raw.h2[q]);
            m[2 * q] = f.x;
            m[2 * q + 1] = f.y;
        }
        float lmax = m[0];
#pragma unroll
        for (int q = 1; q < 8; ++q) lmax = fmaxf(lmax, m[q]);
#pragma unroll
        for (int off = 1; off < 64; off <<= 1) lmax = fmaxf(lmax, __shfl_xor(lmax, off, 64));
        const float thresh = lmax - MARGIN_DOT;

        int base = 0;
#pragma unroll
        for (int s = 0; s < 8; ++s) {
            bool c = (m[s] >= thresh);
            unsigned long long mask = __ballot(c);
            if (c) {
                int pos = base + (int)__popcll(mask & ((1ull << lane) - 1ull));
                if (pos < CAP_ROW) cand[rr][1 + pos] = (ushort)(lane * 8 + s);
            }
            base += (int)__popcll(mask);
        }
        if (lane == 0) cand[rr][0] = (base <= CAP_ROW) ? (ushort)base : (ushort)0xffff;
    }
    __syncthreads();
    if (t < 128)   // 16 rows x 32B, coalesced
        rowcand[(size_t)(row0 + (t >> 3)) * 8 + (t & 7)] = ((const uint*)cand)[t];
}

// ---------- phase 2b: per-subtile exact fp32 rerank (block = subtile) ----------
// (unchanged from rounds 8-10, which passed)
__launch_bounds__(512, 4)
__global__ void vq_subproc_kernel(const float* __restrict__ x, const float* __restrict__ wgt,
                                  const float* __restrict__ t1, const float* __restrict__ e2,
                                  const uint* __restrict__ rowcand,
                                  unsigned long long* __restrict__ bestG) {
    __shared__ float wsub[16][260];     // 16 codes x 256 floats (+4 pad)
    __shared__ float xbuf[32][264];     // one x row per 16-lane group (+8 pad)
    __shared__ int list[CAP_BIN];
    __shared__ int nlist;

    const int t = threadIdx.x;
    const int g = t >> 4, gl = t & 15;              // 32 groups x 16 lanes
    const int st = blockIdx.x;                      // subtile id

    if (t == 0) nlist = 0;
#pragma unroll
    for (int j = 0; j < 2; ++j) {
        const int idx = t + 512 * j;                // code = idx>>6, chunk = idx&63
        *(float4*)&wsub[idx >> 6][(idx & 63) * 4] =
            ((const float4*)(wgt + (size_t)(st * 16 + (idx >> 6)) * CDIM))[idx & 63];
    }
    const float e2v = e2[st * 16 + gl];
    __syncthreads();

    // membership scan: thread handles rows t, t+512, ... (64 iterations)
    for (int it = 0; it < 64; ++it) {
        const int r = t + 512 * it;
        union { struct { uint4 a, b; } qq; ushort h[16]; } rc;
        rc.qq.a = ((const uint4*)rowcand)[(size_t)r * 2];
        rc.qq.b = ((const uint4*)rowcand)[(size_t)r * 2 + 1];
        const uint cnt = rc.h[0];
        bool match = (cnt == 0xffffu);              // marker: candidate everywhere
        const int n = cnt < (uint)CAP_ROW ? (int)cnt : CAP_ROW;
#pragma unroll
        for (int j = 0; j < CAP_ROW; ++j)
            match |= (j < n) && (rc.h[1 + j] == (ushort)st);
        if (match) {
            const int pos = atomicAdd(&nlist, 1);   // LDS atomic (cheap; r3-10 pattern)
            if (pos < CAP_BIN) {
                list[pos] = r;
            } else {
                // overflow fallback (never expected): serial exact rerank of row r
                const float* xp = x + (size_t)r * CDIM;
                const float t1r = t1[r];
                unsigned long long bk = ~0ull;
                for (int kk = 0; kk < 16; ++kk) {
                    float acc = 0.f;
                    for (int c = 0; c < CDIM; ++c) acc = fmaf(xp[c], wsub[kk][c], acc);
                    float d = (t1r + e2[st * 16 + kk]) - 2.0f * acc;
                    unsigned long long key =
                        ((unsigned long long)__float_as_uint(d) << 32) | (uint)(st * 16 + kk);
                    bk = key < bk ? key : bk;
                }
                atomicMin(&bestG[r], bk);
            }
        }
    }
    __syncthreads();

    const int cnt = nlist < CAP_BIN ? nlist : CAP_BIN;
    for (int base = 0; base < cnt; base += 32) {
        const int e = base + g;
        const bool valid = e < cnt;
        int row = 0;
        if (valid) {
            row = list[e];
            const float4* xs = (const float4*)(x + (size_t)row * CDIM);
#pragma unroll
            for (int j = 0; j < 4; ++j)
                *(float4*)&xbuf[g][(gl + 16 * j) * 4] = xs[gl + 16 * j];
        }
        unsigned long long key = ~0ull;
        if (valid) {
            // EXACT accumulation order: sequential c = 0..255, fmaf chain (unchanged).
            float acc = 0.f;
#pragma unroll
            for (int c4 = 0; c4 < 64; ++c4) {
                const float4 wv = *(const float4*)&wsub[gl][c4 * 4];
                const float4 xv = *(const float4*)&xbuf[g][c4 * 4];
                acc = fmaf(xv.x, wv.x, acc);
                acc = fmaf(xv.y, wv.y, acc);
                acc = fmaf(xv.z, wv.z, acc);
                acc = fmaf(xv.w, wv.w, acc);
            }
            const int k = st * 16 + gl;
            float d = (t1[row] + e2v) - 2.0f * acc;  // exact, same chain as rounds 1-10
            key = ((unsigned long long)__float_as_uint(d) << 32) | (uint)k;
        }
#pragma unroll
        for (int off = 1; off < 16; off <<= 1) {
            unsigned long long ok = __shfl_xor(key, off, 64);
            key = ok < key ? ok : key;
        }
        if (gl == 0 && valid) atomicMin(&bestG[row], key);  // scattered: fast (r7-10 validated)
    }
}

// ---------- phase 2c: index write + fused gather (unchanged, validated) ----------
__launch_bounds__(256, 8)
__global__ void vq_gather_kernel(const float* __restrict__ wgt,
                                 const unsigned long long* __restrict__ bestG,
                                 float* __restrict__ out_q, float* __restrict__ out_i) {
    const int t = threadIdx.x;
    const int g = t >> 4, gl = t & 15;
    const int row = blockIdx.x * 16 + g;
    const int bk = (int)(uint)(bestG[row] & 0xffffffffu);
    if (gl == 0) out_i[row] = (float)bk;
    const float4* src = (const float4*)(wgt + (size_t)bk * CDIM);
    float4* dst = (float4*)(out_q + (size_t)row * CDIM);
#pragma unroll
    for (int j = 0; j < 4; ++j) dst[gl + 16 * j] = src[gl + 16 * j];
}

extern "C" void kernel_launch(void* const* d_in, const int* in_sizes, int n_in,
                              void* d_out, int out_size, void* d_ws, size_t ws_size,
                              hipStream_t stream) {
    const float* x = (const float*)d_in[0];   // (8,4096,256) fp32
    const float* wgt = (const float*)d_in[1]; // (8192,256) fp32

    float* out_q = (float*)d_out;
    float* out_i = out_q + (size_t)N_ROWS * CDIM;

    // workspace carve (all 16B aligned): ~53.9 MB total
    char* p = (char*)d_ws;
    float* e2 = (float*)p;                     p += (size_t)KCODES * 4;
    float* t1 = (float*)p;                     p += (size_t)N_ROWS * 4;
    __half* minT = (__half*)p;                 p += (size_t)N_ROWS * NSUB * 2;
    ushort* xb = (ushort*)p;                   p += (size_t)N_ROWS * CDIM * 2;
    ushort* wb = (ushort*)p;                   p += (size_t)KCODES * CDIM * 2;
    unsigned long long* bestG = (unsigned long long*)p; p += (size_t)N_ROWS * 8;
    uint* rowcand = (uint*)p;                  p += (size_t)N_ROWS * 32;

    prep_kernel<<<(N_ROWS + KCODES) / 4, 256, 0, stream>>>(x, wgt, xb, wb, t1, e2, bestG);
    vq_mfma_kernel<<<(N_ROWS / 128) * (KCODES / 128), 256, 0, stream>>>(xb, wb, minT);
    vq_scan_kernel<<<N_ROWS / 16, 256, 0, stream>>>(minT, rowcand);
    vq_subproc_kernel<<<NSUB, 512, 0, stream>>>(x, wgt, t1, e2, rowcand, bestG);
    vq_gather_kernel<<<N_ROWS / 16, 256, 0, stream>>>(wgt, bestG, out_q, out_i);
}

// Round 12
// 304.044 us; speedup vs baseline: 1.1939x; 1.1939x over previous
//
#include <hip/hip_runtime.h>
#include <hip/hip_fp16.h>

#define N_ROWS 32768
#define KCODES 8192
#define CDIM   256
#define NSUB   (KCODES / 16)     // 512 subtiles of 16 codes
// dot-scale margin: covers bf16-dot err + fp16-RTZ storage (~3e-5) + e2 spread (<=1.9e-6).
// Certified need ~1.05e-4; rounds 2-11 passed with this exact value + raw-dot-max semantics.
#define MARGIN_DOT 2.2e-4f
#define CAP_BIN 1024             // per-(subtile,split) LDS list cap (mean ~21); overflow -> fallback
#define SPLIT  4                 // row-splits per subtile (bounds imbalance; traffic invariant)

typedef __attribute__((ext_vector_type(8))) short bf16x8;
typedef __attribute__((ext_vector_type(4))) float f32x4;

// async global->LDS, 16B per lane; LDS dest is wave-uniform base + lane*16 (linear),
// so XOR swizzles are applied to the per-lane GLOBAL source address instead (rule #21).
#define GLOAD_LDS16(g, l)                                                              \
    __builtin_amdgcn_global_load_lds((const __attribute__((address_space(1))) void*)(g), \
                                     (__attribute__((address_space(3))) void*)(l), 16, 0, 0)

__device__ __forceinline__ ushort f2bf_rne(float f) {
    unsigned u = __float_as_uint(f);
    u += 0x7fffu + ((u >> 16) & 1u);
    return (ushort)(u >> 16);
}

// ---------- phase 0: fp32->bf16 convert + row sum-of-squares + bestG init ----------
__global__ void prep_kernel(const float* __restrict__ x, const float* __restrict__ wgt,
                            ushort* __restrict__ xb, ushort* __restrict__ wb,
                            float* __restrict__ t1, float* __restrict__ e2,
                            unsigned long long* __restrict__ bestG) {
    const int gtid = blockIdx.x * blockDim.x + threadIdx.x;
    if (gtid < N_ROWS) bestG[gtid] = ~0ull;      // init per-row best key

    int wave = gtid >> 6;
    int lane = threadIdx.x & 63;
    const float* src; ushort* bdst; float* sqdst; int row;
    if (wave < N_ROWS) { src = x; bdst = xb; sqdst = t1; row = wave; }
    else               { src = wgt; bdst = wb; sqdst = e2; row = wave - N_ROWS; }
    float4 v = *((const float4*)src + (size_t)row * (CDIM / 4) + lane);
    ushort4 o;
    o.x = f2bf_rne(v.x); o.y = f2bf_rne(v.y); o.z = f2bf_rne(v.z); o.w = f2bf_rne(v.w);
    *((ushort4*)bdst + (size_t)row * (CDIM / 4) + lane) = o;
    float s = v.x * v.x + v.y * v.y + v.z * v.z + v.w * v.w;
    for (int off = 32; off; off >>= 1) s += __shfl_down(s, off, 64);
    if (lane == 0) sqdst[row] = s;
}

// ---------- phase 1: 256x128 tile, 8 waves x (64x64), BK=32 dbuf, TRANSPOSED MFMA ----------
// EXACT r10 configuration (measured 166.6 us; best of rounds 8-11). r11's 128x128/4-gang
// variant was 170.5 — gang-count exonerated; the 37% MfmaUtil is the 128-tile L2-staging
// intensity ceiling (64 FLOP/B ~= per-CU L2 share). A 256-tile rewrite is the only
// structural escape; deferred until the tail is lean so attribution stays clean.
__launch_bounds__(512, 3)
__global__ void vq_mfma_kernel(const ushort* __restrict__ xb, const ushort* __restrict__ wb,
                               __half* __restrict__ minT) {
    __shared__ ushort xs[2][256 * 32];   // 2 x 16 KB  (X: 256 rows x 32 cols)
    __shared__ ushort ws_l[2][128 * 32]; // 2 x 8 KB   (W: 128 codes x 32 cols)
    // transposed maxima scratch aliased onto xs[0]; safe: xs[0]'s last READ is chunk 6,
    // every wave passes chunk 7's barrier before any mbT write (r8/r10-verified).
    ushort (*mbT)[264] = (ushort (*)[264])&xs[0][0];

    const int t = threadIdx.x;
    const int w = t >> 6, lane = t & 63;
    const int ln15 = lane & 15, quad = lane >> 4;
    const int rt = blockIdx.x >> 6;     // 128 row tiles
    const int ct = blockIdx.x & 63;     // 64 code tiles
    const int rbase = (w >> 1) * 64;    // wave x-row base (0/64/128/192)
    const int cbase = (w & 1) * 64;     // wave code base (0 or 64)

    const int srow16 = lane >> 2;
    const int schunk = (lane & 3) ^ ((lane >> 3) & 3);   // pre-swizzled source 16B chunk
    const ushort* xsrc = xb + (size_t)(rt * 256 + w * 32 + srow16) * CDIM + schunk * 8;
    const ushort* wsrc = wb + (size_t)(ct * 128 + w * 16 + srow16) * CDIM + schunk * 8;

    f32x4 acc[4][4];                    // [ni: code blocks][mi: x-row blocks]
#pragma unroll
    for (int ni = 0; ni < 4; ++ni)
#pragma unroll
        for (int mi = 0; mi < 4; ++mi)
#pragma unroll
            for (int r = 0; r < 4; ++r) acc[ni][mi][r] = 0.f;

#pragma unroll
    for (int j = 0; j < 2; ++j)
        GLOAD_LDS16(xsrc + (size_t)j * 16 * CDIM, &xs[0][(w * 32 + j * 16) * 32]);
    GLOAD_LDS16(wsrc, &ws_l[0][(w * 16) * 32]);
    __syncthreads();

#pragma unroll
    for (int cc = 0; cc < 8; ++cc) {                  // 8 K-chunks of 32
        const int cur = cc & 1;
        if (cc < 7) {                                  // issue next-chunk loads FIRST
#pragma unroll
            for (int j = 0; j < 2; ++j)
                GLOAD_LDS16(xsrc + (size_t)j * 16 * CDIM + (cc + 1) * 32,
                            &xs[cur ^ 1][(w * 32 + j * 16) * 32]);
            GLOAD_LDS16(wsrc + (cc + 1) * 32, &ws_l[cur ^ 1][(w * 16) * 32]);
        }
        const int swz = (quad ^ ((ln15 >> 1) & 3)) * 8;
        bf16x8 a[4], b[4];
#pragma unroll
        for (int ni = 0; ni < 4; ++ni)
            a[ni] = *(const bf16x8*)&ws_l[cur][(cbase + ni * 16 + ln15) * 32 + swz];
#pragma unroll
        for (int mi = 0; mi < 4; ++mi)
            b[mi] = *(const bf16x8*)&xs[cur][(rbase + mi * 16 + ln15) * 32 + swz];
#pragma unroll
        for (int ni = 0; ni < 4; ++ni)
#pragma unroll
            for (int mi = 0; mi < 4; ++mi)
                acc[ni][mi] = __builtin_amdgcn_mfma_f32_16x16x32_bf16(a[ni], b[mi], acc[ni][mi], 0, 0, 0);
        __syncthreads();          // drains vmcnt -> buf^1 ready; protects buf reuse
    }

    // epilogue (verified rounds 3-11): codes live in {regs x quads}
#pragma unroll
    for (int mi = 0; mi < 4; ++mi) {
        float mxn[4];
#pragma unroll
        for (int ni = 0; ni < 4; ++ni) {
            f32x4 v = acc[ni][mi];
            float mx = fmaxf(fmaxf(v[0], v[1]), fmaxf(v[2], v[3]));
            mx = fmaxf(mx, __shfl_xor(mx, 16, 64));
            mx = fmaxf(mx, __shfl_xor(mx, 32, 64));
            mxn[ni] = mx;
        }
        float sel = quad == 0 ? mxn[0] : quad == 1 ? mxn[1] : quad == 2 ? mxn[2] : mxn[3];
        uint pk = __builtin_bit_cast(uint, __builtin_amdgcn_cvt_pkrtz(sel, sel));  // RTZ as certified
        mbT[(cbase >> 4) + quad][rbase + mi * 16 + ln15] = (ushort)(pk & 0xffffu);
    }
    __syncthreads();
    if (t < 256) {
        // minT layout [rt(128)][ct(64)][row(256)][sub(8)]: dense 4 KB per block
        union { ushort s[8]; uint4 u; } r;
#pragma unroll
        for (int s = 0; s < 8; ++s) r.s[s] = mbT[s][t];
        *(uint4*)(minT + ((size_t)(rt * 64 + ct) * 256 + t) * 8) = r.u;
    }
}

// ---------- phase 2a: per-row threshold (replaces the rowcand scan) ----------
// Same LDS staging + lmax math as the r9/r10 scan (bit-identical values); writes only
// thresh[row] = lmax - MARGIN. Candidate LISTS are gone: membership moves into subproc
// as a direct per-(row,subtile) compare against thresh -- identical predicate, so the
// candidate set and exact winner are unchanged.
__launch_bounds__(256, 8)
__global__ void vq_rowmax_kernel(const __half* __restrict__ minT, float* __restrict__ thresh) {
    __shared__ ushort sm[64][136];       // [ct][row*8+sub], padded stride (17 KB)
    const int t = threadIdx.x, w = t >> 6, lane = t & 63;
    const int row0 = blockIdx.x * 16;

    // stage: thread t covers ct = t>>2, rows 4*(t&3)..+4 (64B contiguous per thread)
    {
        const int ct = t >> 2, c4 = t & 3;
        const uint4* src = (const uint4*)(minT +
            ((((size_t)(row0 >> 8) * 64 + ct) * 256 + (row0 & 255) + c4 * 4) * 8));
#pragma unroll
        for (int i = 0; i < 4; ++i)
            *(uint4*)&sm[ct][(c4 * 4 + i) * 8] = src[i];
    }
    __syncthreads();

    for (int i = 0; i < 4; ++i) {
        const int rr = w * 4 + i;
        union { uint4 u; __half2 h2[4]; } raw;
        raw.u = *(const uint4*)&sm[lane][rr * 8];    // same values as rounds 2-11
        float m[8];
#pragma unroll
        for (int q = 0; q < 4; ++q) {
            float2 f = __half22float2(raw.h2[q]);
            m[2 * q] = f.x;
            m[2 * q + 1] = f.y;
        }
        float lmax = m[0];
#pragma unroll
        for (int q = 1; q < 8; ++q) lmax = fmaxf(lmax, m[q]);
#pragma unroll
        for (int off = 1; off < 64; off <<= 1) lmax = fmaxf(lmax, __shfl_xor(lmax, off, 64));
        if (lane == 0) thresh[row0 + rr] = lmax - MARGIN_DOT;   // same fp32 value as before
    }
}

// ---------- phase 2b: per-(subtile,split) exact fp32 rerank ----------
// Block (st, sp): stage 16-code wgt panel; sweep rows [sp*8192, +8192) reading each
// row's 16B minT record CONTIGUOUSLY (fully-consumed lines); membership = one
// half>=thresh compare (identical predicate to r8-r11's m[s] >= thresh); LDS-list
// compact; then the verified batch body: EXACT c=0..255 fmaf chain, same d formula,
// same (d,k) uint64 key, atomicMin merge -> same winner as all prior rounds.
__launch_bounds__(512, 4)
__global__ void vq_subproc_kernel(const float* __restrict__ x, const float* __restrict__ wgt,
                                  const float* __restrict__ t1, const float* __restrict__ e2,
                                  const __half* __restrict__ minT,
                                  const float* __restrict__ thresh,
                                  unsigned long long* __restrict__ bestG) {
    __shared__ float wsub[16][260];     // 16 codes x 256 floats (+4 pad)
    __shared__ float xbuf[32][264];     // one x row per 16-lane group (+8 pad)
    __shared__ int list[CAP_BIN];
    __shared__ int nlist;

    const int t = threadIdx.x;
    const int g = t >> 4, gl = t & 15;              // 32 groups x 16 lanes
    const int st = blockIdx.x >> 2;                 // subtile id
    const int sp = blockIdx.x & (SPLIT - 1);        // row split
    const int ct = st >> 3, sub = st & 7;

    if (t == 0) nlist = 0;
#pragma unroll
    for (int j = 0; j < 2; ++j) {
        const int idx = t + 512 * j;                // code = idx>>6, chunk = idx&63
        *(float4*)&wsub[idx >> 6][(idx & 63) * 4] =
            ((const float4*)(wgt + (size_t)(st * 16 + (idx >> 6)) * CDIM))[idx & 63];
    }
    const float e2v = e2[st * 16 + gl];
    __syncthreads();

    // membership sweep: 8192 rows, thread-strided; 16B record per row, contiguous in r
    for (int it = 0; it < 16; ++it) {
        const int r = sp * (N_ROWS / SPLIT) + t + 512 * it;
        const uint4 mg = *(const uint4*)(minT +
            ((((size_t)(r >> 8) * 64 + ct) * 256 + (r & 255)) * 8));
        // extract half #sub (sub is block-uniform; select via ?: to stay in registers)
        const uint word = (sub >> 1) == 0 ? mg.x : (sub >> 1) == 1 ? mg.y
                        : (sub >> 1) == 2 ? mg.z : mg.w;
        const ushort hbits = (sub & 1) ? (ushort)(word >> 16) : (ushort)(word & 0xffffu);
        const float ms = __half2float(__builtin_bit_cast(__half, hbits));
        if (ms >= thresh[r]) {
            const int pos = atomicAdd(&nlist, 1);   // LDS atomic (cheap; r3-11 pattern)
            if (pos < CAP_BIN) {
                list[pos] = r;
            } else {
                // overflow fallback (never expected at mean ~21): serial exact rerank
                const float* xp = x + (size_t)r * CDIM;
                const float t1r = t1[r];
                unsigned long long bk = ~0ull;
                for (int kk = 0; kk < 16; ++kk) {
                    float acc = 0.f;
                    for (int c = 0; c < CDIM; ++c) acc = fmaf(xp[c], wsub[kk][c], acc);
                    float d = (t1r + e2[st * 16 + kk]) - 2.0f * acc;
                    unsigned long long key =
                        ((unsigned long long)__float_as_uint(d) << 32) | (uint)(st * 16 + kk);
                    bk = key < bk ? key : bk;
                }
                atomicMin(&bestG[r], bk);
            }
        }
    }
    __syncthreads();

    const int cnt = nlist < CAP_BIN ? nlist : CAP_BIN;
    for (int base = 0; base < cnt; base += 32) {
        const int e = base + g;
        const bool valid = e < cnt;
        int row = 0;
        if (valid) {
            row = list[e];
            const float4* xs = (const float4*)(x + (size_t)row * CDIM);
#pragma unroll
            for (int j = 0; j < 4; ++j)
                *(float4*)&xbuf[g][(gl + 16 * j) * 4] = xs[gl + 16 * j];
        }
        unsigned long long key = ~0ull;
        if (valid) {
            // EXACT accumulation order: sequential c = 0..255, fmaf chain (unchanged).
            float acc = 0.f;
#pragma unroll
            for (int c4 = 0; c4 < 64; ++c4) {
                const float4 wv = *(const float4*)&wsub[gl][c4 * 4];
                const float4 xv = *(const float4*)&xbuf[g][c4 * 4];
                acc = fmaf(xv.x, wv.x, acc);
                acc = fmaf(xv.y, wv.y, acc);
                acc = fmaf(xv.z, wv.z, acc);
                acc = fmaf(xv.w, wv.w, acc);
            }
            const int k = st * 16 + gl;
            float d = (t1[row] + e2v) - 2.0f * acc;  // exact, same chain as rounds 1-11
            key = ((unsigned long long)__float_as_uint(d) << 32) | (uint)k;
        }
#pragma unroll
        for (int off = 1; off < 16; off <<= 1) {
            unsigned long long ok = __shfl_xor(key, off, 64);
            key = ok < key ? ok : key;
        }
        if (gl == 0 && valid) atomicMin(&bestG[row], key);  // scattered: fast (r7-11 validated)
    }
}

// ---------- phase 2c: index write + fused gather (unchanged, validated) ----------
__launch_bounds__(256, 8)
__global__ void vq_gather_kernel(const float* __restrict__ wgt,
                                 const unsigned long long* __restrict__ bestG,
                                 float* __restrict__ out_q, float* __restrict__ out_i) {
    const int t = threadIdx.x;
    const int g = t >> 4, gl = t & 15;
    const int row = blockIdx.x * 16 + g;
    const int bk = (int)(uint)(bestG[row] & 0xffffffffu);
    if (gl == 0) out_i[row] = (float)bk;
    const float4* src = (const float4*)(wgt + (size_t)bk * CDIM);
    float4* dst = (float4*)(out_q + (size_t)row * CDIM);
#pragma unroll
    for (int j = 0; j < 4; ++j) dst[gl + 16 * j] = src[gl + 16 * j];
}

extern "C" void kernel_launch(void* const* d_in, const int* in_sizes, int n_in,
                              void* d_out, int out_size, void* d_ws, size_t ws_size,
                              hipStream_t stream) {
    const float* x = (const float*)d_in[0];   // (8,4096,256) fp32
    const float* wgt = (const float*)d_in[1]; // (8192,256) fp32

    float* out_q = (float*)d_out;
    float* out_i = out_q + (size_t)N_ROWS * CDIM;

    // workspace carve (all 16B aligned): ~53 MB total
    char* p = (char*)d_ws;
    float* e2 = (float*)p;                     p += (size_t)KCODES * 4;
    float* t1 = (float*)p;                     p += (size_t)N_ROWS * 4;
    __half* minT = (__half*)p;                 p += (size_t)N_ROWS * NSUB * 2;
    ushort* xb = (ushort*)p;                   p += (size_t)N_ROWS * CDIM * 2;
    ushort* wb = (ushort*)p;                   p += (size_t)KCODES * CDIM * 2;
    unsigned long long* bestG = (unsigned long long*)p; p += (size_t)N_ROWS * 8;
    float* thresh = (float*)p;                 p += (size_t)N_ROWS * 4;

    prep_kernel<<<(N_ROWS + KCODES) / 4, 256, 0, stream>>>(x, wgt, xb, wb, t1, e2, bestG);
    vq_mfma_kernel<<<(N_ROWS / 256) * (KCODES / 128), 512, 0, stream>>>(xb, wb, minT);
    vq_rowmax_kernel<<<N_ROWS / 16, 256, 0, stream>>>(minT, thresh);
    vq_subproc_kernel<<<NSUB * SPLIT, 512, 0, stream>>>(x, wgt, t1, e2, minT, thresh, bestG);
    vq_gather_kernel<<<N_ROWS / 16, 256, 0, stream>>>(wgt, bestG, out_q, out_i);
}

// Round 13
// 301.269 us; speedup vs baseline: 1.2049x; 1.0092x over previous
//
#include <hip/hip_runtime.h>
#include <hip/hip_fp16.h>

#define N_ROWS 32768
#define KCODES 8192
#define CDIM   256
#define NSUB   (KCODES / 16)     // 512 subtiles of 16 codes
// dot-scale margin: covers bf16-dot err + fp16-RTZ storage (~3e-5) + e2 spread (<=1.9e-6).
// Certified need ~1.05e-4; rounds 2-12 passed with this exact value + raw-dot-max semantics.
#define MARGIN_DOT 2.2e-4f
#define CAP_SUB 768              // per-(sub,split) LDS list cap (mean ~27); overflow -> fallback
#define SPLIT  4                 // row-splits per ct-panel (256 blocks total)

typedef __attribute__((ext_vector_type(8))) short bf16x8;
typedef __attribute__((ext_vector_type(4))) float f32x4;

// async global->LDS, 16B per lane; LDS dest is wave-uniform base + lane*16 (linear),
// so XOR swizzles are applied to the per-lane GLOBAL source address instead (rule #21).
#define GLOAD_LDS16(g, l)                                                              \
    __builtin_amdgcn_global_load_lds((const __attribute__((address_space(1))) void*)(g), \
                                     (__attribute__((address_space(3))) void*)(l), 16, 0, 0)

__device__ __forceinline__ ushort f2bf_rne(float f) {
    unsigned u = __float_as_uint(f);
    u += 0x7fffu + ((u >> 16) & 1u);
    return (ushort)(u >> 16);
}

// ---------- phase 0: fp32->bf16 convert + row sum-of-squares + bestG init ----------
__global__ void prep_kernel(const float* __restrict__ x, const float* __restrict__ wgt,
                            ushort* __restrict__ xb, ushort* __restrict__ wb,
                            float* __restrict__ t1, float* __restrict__ e2,
                            unsigned long long* __restrict__ bestG) {
    const int gtid = blockIdx.x * blockDim.x + threadIdx.x;
    if (gtid < N_ROWS) bestG[gtid] = ~0ull;      // init per-row best key

    int wave = gtid >> 6;
    int lane = threadIdx.x & 63;
    const float* src; ushort* bdst; float* sqdst; int row;
    if (wave < N_ROWS) { src = x; bdst = xb; sqdst = t1; row = wave; }
    else               { src = wgt; bdst = wb; sqdst = e2; row = wave - N_ROWS; }
    float4 v = *((const float4*)src + (size_t)row * (CDIM / 4) + lane);
    ushort4 o;
    o.x = f2bf_rne(v.x); o.y = f2bf_rne(v.y); o.z = f2bf_rne(v.z); o.w = f2bf_rne(v.w);
    *((ushort4*)bdst + (size_t)row * (CDIM / 4) + lane) = o;
    float s = v.x * v.x + v.y * v.y + v.z * v.z + v.w * v.w;
    for (int off = 32; off; off >>= 1) s += __shfl_down(s, off, 64);
    if (lane == 0) sqdst[row] = s;
}

// ---------- phase 1: 256x128 tile, 8 waves x (64x64), BK=32 dbuf, TRANSPOSED MFMA ----------
// FROZEN r10/r12 configuration (166.3 us, 827 TF = the m97-structure ceiling; r10-r12
// agree within noise). The only escape is a 256-tile 8-phase rewrite — next round's
// candidate now that the tail is lean.
__launch_bounds__(512, 3)
__global__ void vq_mfma_kernel(const ushort* __restrict__ xb, const ushort* __restrict__ wb,
                               __half* __restrict__ minT) {
    __shared__ ushort xs[2][256 * 32];   // 2 x 16 KB  (X: 256 rows x 32 cols)
    __shared__ ushort ws_l[2][128 * 32]; // 2 x 8 KB   (W: 128 codes x 32 cols)
    // transposed maxima scratch aliased onto xs[0]; safe: xs[0]'s last READ is chunk 6,
    // every wave passes chunk 7's barrier before any mbT write (r8-r12 verified).
    ushort (*mbT)[264] = (ushort (*)[264])&xs[0][0];

    const int t = threadIdx.x;
    const int w = t >> 6, lane = t & 63;
    const int ln15 = lane & 15, quad = lane >> 4;
    const int rt = blockIdx.x >> 6;     // 128 row tiles
    const int ct = blockIdx.x & 63;     // 64 code tiles
    const int rbase = (w >> 1) * 64;    // wave x-row base (0/64/128/192)
    const int cbase = (w & 1) * 64;     // wave code base (0 or 64)

    const int srow16 = lane >> 2;
    const int schunk = (lane & 3) ^ ((lane >> 3) & 3);   // pre-swizzled source 16B chunk
    const ushort* xsrc = xb + (size_t)(rt * 256 + w * 32 + srow16) * CDIM + schunk * 8;
    const ushort* wsrc = wb + (size_t)(ct * 128 + w * 16 + srow16) * CDIM + schunk * 8;

    f32x4 acc[4][4];                    // [ni: code blocks][mi: x-row blocks]
#pragma unroll
    for (int ni = 0; ni < 4; ++ni)
#pragma unroll
        for (int mi = 0; mi < 4; ++mi)
#pragma unroll
            for (int r = 0; r < 4; ++r) acc[ni][mi][r] = 0.f;

#pragma unroll
    for (int j = 0; j < 2; ++j)
        GLOAD_LDS16(xsrc + (size_t)j * 16 * CDIM, &xs[0][(w * 32 + j * 16) * 32]);
    GLOAD_LDS16(wsrc, &ws_l[0][(w * 16) * 32]);
    __syncthreads();

#pragma unroll
    for (int cc = 0; cc < 8; ++cc) {                  // 8 K-chunks of 32
        const int cur = cc & 1;
        if (cc < 7) {                                  // issue next-chunk loads FIRST
#pragma unroll
            for (int j = 0; j < 2; ++j)
                GLOAD_LDS16(xsrc + (size_t)j * 16 * CDIM + (cc + 1) * 32,
                            &xs[cur ^ 1][(w * 32 + j * 16) * 32]);
            GLOAD_LDS16(wsrc + (cc + 1) * 32, &ws_l[cur ^ 1][(w * 16) * 32]);
        }
        const int swz = (quad ^ ((ln15 >> 1) & 3)) * 8;
        bf16x8 a[4], b[4];
#pragma unroll
        for (int ni = 0; ni < 4; ++ni)
            a[ni] = *(const bf16x8*)&ws_l[cur][(cbase + ni * 16 + ln15) * 32 + swz];
#pragma unroll
        for (int mi = 0; mi < 4; ++mi)
            b[mi] = *(const bf16x8*)&xs[cur][(rbase + mi * 16 + ln15) * 32 + swz];
#pragma unroll
        for (int ni = 0; ni < 4; ++ni)
#pragma unroll
            for (int mi = 0; mi < 4; ++mi)
                acc[ni][mi] = __builtin_amdgcn_mfma_f32_16x16x32_bf16(a[ni], b[mi], acc[ni][mi], 0, 0, 0);
        __syncthreads();          // drains vmcnt -> buf^1 ready; protects buf reuse
    }

    // epilogue (verified rounds 3-12): codes live in {regs x quads}
#pragma unroll
    for (int mi = 0; mi < 4; ++mi) {
        float mxn[4];
#pragma unroll
        for (int ni = 0; ni < 4; ++ni) {
            f32x4 v = acc[ni][mi];
            float mx = fmaxf(fmaxf(v[0], v[1]), fmaxf(v[2], v[3]));
            mx = fmaxf(mx, __shfl_xor(mx, 16, 64));
            mx = fmaxf(mx, __shfl_xor(mx, 32, 64));
            mxn[ni] = mx;
        }
        float sel = quad == 0 ? mxn[0] : quad == 1 ? mxn[1] : quad == 2 ? mxn[2] : mxn[3];
        uint pk = __builtin_bit_cast(uint, __builtin_amdgcn_cvt_pkrtz(sel, sel));  // RTZ as certified
        mbT[(cbase >> 4) + quad][rbase + mi * 16 + ln15] = (ushort)(pk & 0xffffu);
    }
    __syncthreads();
    if (t < 256) {
        // minT layout [rt(128)][ct(64)][row(256)][sub(8)]: dense 4 KB per block
        union { ushort s[8]; uint4 u; } r;
#pragma unroll
        for (int s = 0; s < 8; ++s) r.s[s] = mbT[s][t];
        *(uint4*)(minT + ((size_t)(rt * 64 + ct) * 256 + t) * 8) = r.u;
    }
}

// ---------- phase 2a: per-row threshold (unchanged from round 12, which passed) ----------
__launch_bounds__(256, 8)
__global__ void vq_rowmax_kernel(const __half* __restrict__ minT, float* __restrict__ thresh) {
    __shared__ ushort sm[64][136];       // [ct][row*8+sub], padded stride (17 KB)
    const int t = threadIdx.x, w = t >> 6, lane = t & 63;
    const int row0 = blockIdx.x * 16;

    // stage: thread t covers ct = t>>2, rows 4*(t&3)..+4 (64B contiguous per thread)
    {
        const int ct = t >> 2, c4 = t & 3;
        const uint4* src = (const uint4*)(minT +
            ((((size_t)(row0 >> 8) * 64 + ct) * 256 + (row0 & 255) + c4 * 4) * 8));
#pragma unroll
        for (int i = 0; i < 4; ++i)
            *(uint4*)&sm[ct][(c4 * 4 + i) * 8] = src[i];
    }
    __syncthreads();

    for (int i = 0; i < 4; ++i) {
        const int rr = w * 4 + i;
        union { uint4 u; __half2 h2[4]; } raw;
        raw.u = *(const uint4*)&sm[lane][rr * 8];    // same values as rounds 2-12
        float m[8];
#pragma unroll
        for (int q = 0; q < 4; ++q) {
            float2 f = __half22float2(raw.h2[q]);
            m[2 * q] = f.x;
            m[2 * q + 1] = f.y;
        }
        float lmax = m[0];
#pragma unroll
        for (int q = 1; q < 8; ++q) lmax = fmaxf(lmax, m[q]);
#pragma unroll
        for (int off = 1; off < 64; off <<= 1) lmax = fmaxf(lmax, __shfl_xor(lmax, off, 64));
        if (lane == 0) thresh[row0 + rr] = lmax - MARGIN_DOT;   // same fp32 value as before
    }
}

// ---------- phase 2b: per-(ct,split) exact fp32 rerank, record read ONCE ----------
// Round-12 traffic analysis: the per-(subtile,split) sweep read each 16B minT record
// 8x (once per sub) + thresh 8x = 320 MB -> the dominant tail cost. This version: one
// block per (ct,split) reads each record ONCE (32 MB total), unpacks all 8 subtile
// maxima (same __half22float2), compares each to thresh[r] (IDENTICAL predicate ->
// identical candidate sets), and pushes rows into 8 per-sub LDS lists. Then 8
// sequential dot phases run the verbatim r8-r12 batch body: EXACT c=0..255 fmaf chain,
// same d formula, same (d,k) uint64 key, same atomicMin merge -> same winner.
// Overflow fallback reads wgt from GLOBAL (bit-identical values to the LDS copy).
__launch_bounds__(512, 2)
__global__ void vq_subproc_kernel(const float* __restrict__ x, const float* __restrict__ wgt,
                                  const float* __restrict__ t1, const float* __restrict__ e2,
                                  const __half* __restrict__ minT,
                                  const float* __restrict__ thresh,
                                  unsigned long long* __restrict__ bestG) {
    __shared__ float wsub[16][260];     // 16 codes x 256 floats (+4 pad), restaged per sub
    __shared__ float xbuf[32][264];     // one x row per 16-lane group (+8 pad)
    __shared__ int lists[8][CAP_SUB];   // per-sub candidate rows (24 KB)
    __shared__ int cnts[8];

    const int t = threadIdx.x;
    const int g = t >> 4, gl = t & 15;              // 32 groups x 16 lanes
    const int ct = blockIdx.x >> 2;                 // ct panel (64)
    const int sp = blockIdx.x & (SPLIT - 1);        // row split (4)

    if (t < 8) cnts[t] = 0;
    __syncthreads();

    // membership sweep: 8192 rows, thread-strided; ONE 16B record + one thresh per row
    for (int it = 0; it < 16; ++it) {
        const int r = sp * (N_ROWS / SPLIT) + t + 512 * it;
        union { uint4 u; __half2 h2[4]; } raw;
        raw.u = *(const uint4*)(minT + ((((size_t)(r >> 8) * 64 + ct) * 256 + (r & 255)) * 8));
        const float th = thresh[r];
        float m[8];
#pragma unroll
        for (int q = 0; q < 4; ++q) {
            float2 f = __half22float2(raw.h2[q]);
            m[2 * q] = f.x;
            m[2 * q + 1] = f.y;
        }
#pragma unroll
        for (int s = 0; s < 8; ++s) {
            if (m[s] >= th) {                        // identical predicate to r8-r12
                const int pos = atomicAdd(&cnts[s], 1);   // LDS atomic (r3-12 pattern)
                if (pos < CAP_SUB) {
                    lists[s][pos] = r;
                } else {
                    // overflow fallback (never expected at mean ~27): serial exact
                    // rerank from GLOBAL wgt (same values as the wsub copy).
                    const int st = ct * 8 + s;
                    const float* xp = x + (size_t)r * CDIM;
                    const float t1r = t1[r];
                    unsigned long long bk = ~0ull;
                    for (int kk = 0; kk < 16; ++kk) {
                        const float* wp = wgt + (size_t)(st * 16 + kk) * CDIM;
                        float acc = 0.f;
                        for (int c = 0; c < CDIM; ++c) acc = fmaf(xp[c], wp[c], acc);
                        float d = (t1r + e2[st * 16 + kk]) - 2.0f * acc;
                        unsigned long long key =
                            ((unsigned long long)__float_as_uint(d) << 32) | (uint)(st * 16 + kk);
                        bk = key < bk ? key : bk;
                    }
                    atomicMin(&bestG[r], bk);
                }
            }
        }
    }
    __syncthreads();

    // 8 dot phases: stage wgt panel for sub s, process its list (verbatim r8-r12 body)
    for (int s = 0; s < 8; ++s) {
        const int st = ct * 8 + s;
        __syncthreads();                             // previous phase's readers done
#pragma unroll
        for (int j = 0; j < 2; ++j) {
            const int idx = t + 512 * j;             // code = idx>>6, chunk = idx&63
            *(float4*)&wsub[idx >> 6][(idx & 63) * 4] =
                ((const float4*)(wgt + (size_t)(st * 16 + (idx >> 6)) * CDIM))[idx & 63];
        }
        __syncthreads();
        const float e2v = e2[st * 16 + gl];
        const int cnt = cnts[s] < CAP_SUB ? cnts[s] : CAP_SUB;

        for (int base = 0; base < cnt; base += 32) {
            const int e = base + g;
            const bool valid = e < cnt;
            int row = 0;
            if (valid) {
                row = lists[s][e];
                const float4* xs = (const float4*)(x + (size_t)row * CDIM);
#pragma unroll
                for (int j = 0; j < 4; ++j)
                    *(float4*)&xbuf[g][(gl + 16 * j) * 4] = xs[gl + 16 * j];
            }
            unsigned long long key = ~0ull;
            if (valid) {
                // EXACT accumulation order: sequential c = 0..255, fmaf chain.
                float acc = 0.f;
#pragma unroll
                for (int c4 = 0; c4 < 64; ++c4) {
                    const float4 wv = *(const float4*)&wsub[gl][c4 * 4];
                    const float4 xv = *(const float4*)&xbuf[g][c4 * 4];
                    acc = fmaf(xv.x, wv.x, acc);
                    acc = fmaf(xv.y, wv.y, acc);
                    acc = fmaf(xv.z, wv.z, acc);
                    acc = fmaf(xv.w, wv.w, acc);
                }
                const int k = st * 16 + gl;
                float d = (t1[row] + e2v) - 2.0f * acc;  // exact, same chain as r1-r12
                key = ((unsigned long long)__float_as_uint(d) << 32) | (uint)k;
            }
#pragma unroll
            for (int off = 1; off < 16; off <<= 1) {
                unsigned long long ok = __shfl_xor(key, off, 64);
                key = ok < key ? ok : key;
            }
            if (gl == 0 && valid) atomicMin(&bestG[row], key);  // scattered: fast
        }
    }
}

// ---------- phase 2c: index write + fused gather (unchanged, validated) ----------
__launch_bounds__(256, 8)
__global__ void vq_gather_kernel(const float* __restrict__ wgt,
                                 const unsigned long long* __restrict__ bestG,
                                 float* __restrict__ out_q, float* __restrict__ out_i) {
    const int t = threadIdx.x;
    const int g = t >> 4, gl = t & 15;
    const int row = blockIdx.x * 16 + g;
    const int bk = (int)(uint)(bestG[row] & 0xffffffffu);
    if (gl == 0) out_i[row] = (float)bk;
    const float4* src = (const float4*)(wgt + (size_t)bk * CDIM);
    float4* dst = (float4*)(out_q + (size_t)row * CDIM);
#pragma unroll
    for (int j = 0; j < 4; ++j) dst[gl + 16 * j] = src[gl + 16 * j];
}

extern "C" void kernel_launch(void* const* d_in, const int* in_sizes, int n_in,
                              void* d_out, int out_size, void* d_ws, size_t ws_size,
                              hipStream_t stream) {
    const float* x = (const float*)d_in[0];   // (8,4096,256) fp32
    const float* wgt = (const float*)d_in[1]; // (8192,256) fp32

    float* out_q = (float*)d_out;
    float* out_i = out_q + (size_t)N_ROWS * CDIM;

    // workspace carve (all 16B aligned): ~53 MB total
    char* p = (char*)d_ws;
    float* e2 = (float*)p;                     p += (size_t)KCODES * 4;
    float* t1 = (float*)p;                     p += (size_t)N_ROWS * 4;
    __half* minT = (__half*)p;                 p += (size_t)N_ROWS * NSUB * 2;
    ushort* xb = (ushort*)p;                   p += (size_t)N_ROWS * CDIM * 2;
    ushort* wb = (ushort*)p;                   p += (size_t)KCODES * CDIM * 2;
    unsigned long long* bestG = (unsigned long long*)p; p += (size_t)N_ROWS * 8;
    float* thresh = (float*)p;                 p += (size_t)N_ROWS * 4;

    prep_kernel<<<(N_ROWS + KCODES) / 4, 256, 0, stream>>>(x, wgt, xb, wb, t1, e2, bestG);
    vq_mfma_kernel<<<(N_ROWS / 256) * (KCODES / 128), 512, 0, stream>>>(xb, wb, minT);
    vq_rowmax_kernel<<<N_ROWS / 16, 256, 0, stream>>>(minT, thresh);
    vq_subproc_kernel<<<64 * SPLIT, 512, 0, stream>>>(x, wgt, t1, e2, minT, thresh, bestG);
    vq_gather_kernel<<<N_ROWS / 16, 256, 0, stream>>>(wgt, bestG, out_q, out_i);
}